// Round 1
// baseline (940.317 us; speedup 1.0000x reference)
//
#include <hip/hip_runtime.h>
#include <hip/hip_bf16.h>
#include <math.h>

#define DI __device__ __forceinline__

typedef float  f32x4 __attribute__((ext_vector_type(4)));
typedef short  bf8   __attribute__((ext_vector_type(8)));
typedef unsigned short u16;

static constexpr int TT = 8192;   // T edges
static constexpr int KK = 32;     // CN tokens per edge
static constexpr int CC = 128;    // channels

DI u16 f2bf(float x){ union{float f; unsigned u;} v; v.f = x; unsigned r = v.u + 0x7FFFu + ((v.u>>16)&1u); return (u16)(r>>16); }
DI float bf2f(u16 b){ union{unsigned u; float f;} v; v.u = ((unsigned)b)<<16; return v.f; }
DI unsigned pk2(float a, float b){ return (unsigned)f2bf(a) | ((unsigned)f2bf(b)<<16); }
DI f32x4 mfma16(bf8 a, bf8 b, f32x4 c){ return __builtin_amdgcn_mfma_f32_16x16x32_bf16(a, b, c, 0, 0, 0); }
// swizzled LDS byte offset: row-major [*][stride bytes], xor row bits into 16B-slot bits
DI int soff(int r, int c, int stride, int mask){ return r*stride + ((c*2) ^ ((r&mask)<<4)); }

// ------------------------------------------------------------------
// K0: convert the 12 weight matrices fp32 -> bf16 blob in ws
// order: tok_w qkv_w out_w ff1_w ff2_w xcn_w1 xcn_w2 xcn_w3 xij_w1 xij_w2 lin_w1 lin_w2
// ------------------------------------------------------------------
struct WP { const float* p[12]; };

__global__ void k0_convert(WP wp, u16* __restrict__ dst){
  const int sz[12] = {65536,49152,16384,65536,65536,32768,65536,65536,32768,65536,65536,256};
  int gid = blockIdx.x*256 + threadIdx.x;   // total 590080 = 2305*256
  int off = 0;
  #pragma unroll
  for (int s = 0; s < 12; s++){
    if (gid < off + sz[s]){ dst[gid] = f2bf(wp.p[s][gid - off]); return; }
    off += sz[s];
  }
}

// ------------------------------------------------------------------
// K1: fused gather + tokenlin + transformer layer + masked mean pool
// 1 block = 4 edges = 128 token rows, 256 threads (4 waves).
// wave w owns output columns [32w, 32w+32) for all GEMMs (n-split),
// and owns edge w for the attention phase (m-split).
// ------------------------------------------------------------------
// LDS offsets (bytes)
#define O_TOK  0        // [128][128] bf16 residual (swizzled, stride 256, mask 7)
#define O_H    32768    // [128][128] bf16 h / xw staging
#define O_CTX  65536    // [128][128] bf16 ctx / y1-chunk
#define O_Q    98304    // [128][32] bf16 q (2 heads)  (stride 64, mask 3)
#define O_K2L  106496   // [128][32] bf16 k
#define O_VT   114688   // [32][128] bf16 v^T (stride 256, mask 7)
#define O_ATT  122880   // 4 x [32][32] bf16 attn (stride 64, mask 3)
#define O_CI   131072   // [4][128] f32 per-edge tokenlin contribution
#define O_CNT  133120   // int[4]
#define O_COLS 133136   // int[128]
#define LDS_K1 133664

DI void layernorm128(const char* src, char* dst, const float* __restrict__ g,
                     const float* __restrict__ bta, int tid){
  int r = tid >> 1, hf = tid & 1;
  float v[64]; float s = 0.f, sq = 0.f;
  #pragma unroll
  for (int i = 0; i < 8; i++){
    bf8 h8 = *(const bf8*)(src + soff(r, hf*64 + i*8, 256, 7));
    #pragma unroll
    for (int j = 0; j < 8; j++){ float f = bf2f((u16)h8[j]); v[i*8+j] = f; s += f; sq += f*f; }
  }
  s  += __shfl_xor(s, 1);
  sq += __shfl_xor(sq, 1);
  float mu = s * (1.f/128.f);
  float rstd = rsqrtf(sq*(1.f/128.f) - mu*mu + 1e-5f);
  #pragma unroll
  for (int i = 0; i < 8; i++){
    bf8 o;
    #pragma unroll
    for (int j = 0; j < 8; j++){
      int c = hf*64 + i*8 + j;
      o[j] = (short)f2bf((v[i*8+j] - mu)*rstd*g[c] + bta[c]);
    }
    *(bf8*)(dst + soff(r, hf*64 + i*8, 256, 7)) = o;
  }
}

// n-split GEMM: [128 rows x 128 cols] += LDS_A[128][128k] * W^T, K=128
DI void gemm128(const char* sA, const u16* __restrict__ W, int ldk, int koff,
                int w, int l15, int lg, f32x4 (&acc)[8][2]){
  #pragma unroll
  for (int ks = 0; ks < 4; ks++){
    bf8 b0 = *(const bf8*)(W + ((2*w+0)*16 + l15)*ldk + koff + ks*32 + lg*8);
    bf8 b1 = *(const bf8*)(W + ((2*w+1)*16 + l15)*ldk + koff + ks*32 + lg*8);
    #pragma unroll
    for (int mt = 0; mt < 8; mt++){
      bf8 a = *(const bf8*)(sA + soff(mt*16 + l15, ks*32 + lg*8, 256, 7));
      acc[mt][0] = mfma16(a, b0, acc[mt][0]);
      acc[mt][1] = mfma16(a, b1, acc[mt][1]);
    }
  }
}

__global__ __launch_bounds__(256, 1)
void k1_fused(const float* __restrict__ x, const int* __restrict__ tar_ei,
              const int* __restrict__ cn_cols, const int* __restrict__ cn_counts,
              const float* __restrict__ tok_b,
              const float* __restrict__ ln1_g, const float* __restrict__ ln1_b,
              const float* __restrict__ qkv_b, const float* __restrict__ out_b,
              const float* __restrict__ ln2_g, const float* __restrict__ ln2_b,
              const float* __restrict__ ff1_b, const float* __restrict__ ff2_b,
              const u16* __restrict__ wbf,
              float* __restrict__ xcn_out, float* __restrict__ xij_out)
{
  __shared__ __align__(16) char sm[LDS_K1];
  const int tid = threadIdx.x;
  const int w = tid >> 6, l = tid & 63, l15 = l & 15, lg = l >> 4;
  const int t0 = blockIdx.x * 4;

  const u16* wtok = wbf;            // [128][512]
  const u16* wqkv = wbf + 65536;    // [384][128]
  const u16* wout = wbf + 114688;   // [128][128]
  const u16* wff1 = wbf + 131072;   // [512][128]
  const u16* wff2 = wbf + 196608;   // [128][512]

  int*   scnt  = (int*)(sm + O_CNT);
  int*   scols = (int*)(sm + O_COLS);
  float* sci   = (float*)(sm + O_CI);
  const f32x4 zf = {0.f, 0.f, 0.f, 0.f};

  // ---- phase 0a: indices + zero the ci A-matrix (aliases O_Q region)
  if (tid < 4)   scnt[tid]  = cn_counts[t0 + tid];
  if (tid < 128) scols[tid] = cn_cols[(t0 + (tid >> 5))*KK + (tid & 31)];
  {
    unsigned* z = (unsigned*)(sm + O_Q);  // [16][384] bf16 = 3072 u32
    #pragma unroll
    for (int i = 0; i < 12; i++) z[tid + i*256] = 0;
  }
  __syncthreads();

  // ---- phase 0b: gather xw -> sH (bf16, swizzled). 2 threads per row.
  {
    int r = tid >> 1, hf = tid & 1;
    const float4* xs = (const float4*)(x + (size_t)scols[r]*CC) + hf*16;
    #pragma unroll
    for (int i = 0; i < 8; i++){
      float4 a = xs[2*i], b = xs[2*i+1];
      bf8 v;
      v[0]=(short)f2bf(a.x); v[1]=(short)f2bf(a.y); v[2]=(short)f2bf(a.z); v[3]=(short)f2bf(a.w);
      v[4]=(short)f2bf(b.x); v[5]=(short)f2bf(b.y); v[6]=(short)f2bf(b.z); v[7]=(short)f2bf(b.w);
      *(bf8*)(sm + O_H + soff(r, hf*64 + i*8, 256, 7)) = v;
    }
  }
  // ---- phase 0c: stage [xi|xj|xi*xj] rows (edge per wave) + write xij to ws
  {
    int e = w, c0 = l*2;
    int ti = tar_ei[t0 + e], tj = tar_ei[TT + t0 + e];
    float vix = x[(size_t)ti*CC + c0], viy = x[(size_t)ti*CC + c0 + 1];
    float vjx = x[(size_t)tj*CC + c0], vjy = x[(size_t)tj*CC + c0 + 1];
    float px = vix*vjx, py = viy*vjy;
    xij_out[(size_t)(t0+e)*CC + c0]     = px;
    xij_out[(size_t)(t0+e)*CC + c0 + 1] = py;
    unsigned* arow = (unsigned*)(sm + O_Q + e*768);   // row e of [16][384] bf16
    arow[l]       = pk2(vix, viy);
    arow[64 + l]  = pk2(vjx, vjy);
    arow[128 + l] = pk2(px, py);
  }
  __syncthreads();

  // ---- phase 0d: ci GEMM (K=384) -> sci = per-edge tokenlin part + tok_b
  {
    f32x4 cacc[2] = {zf, zf};
    #pragma unroll
    for (int ks = 0; ks < 12; ks++){
      bf8 a = *(const bf8*)(sm + O_Q + l15*768 + (ks*32 + lg*8)*2);
      #pragma unroll
      for (int nt = 0; nt < 2; nt++){
        int wrow = (2*w + nt)*16 + l15;
        bf8 b = *(const bf8*)(wtok + wrow*512 + 128 + ks*32 + lg*8);
        cacc[nt] = mfma16(a, b, cacc[nt]);
      }
    }
    if (lg == 0){
      #pragma unroll
      for (int nt = 0; nt < 2; nt++){
        int colg = (2*w + nt)*16 + l15;
        float tb = tok_b[colg];
        #pragma unroll
        for (int e = 0; e < 4; e++) sci[e*128 + colg] = cacc[nt][e] + tb;
      }
    }
  }
  // ---- phase 0e: tok GEMM (xw part) + relu epilogue -> sTok
  {
    f32x4 acc[8][2];
    #pragma unroll
    for (int mt = 0; mt < 8; mt++){ acc[mt][0] = zf; acc[mt][1] = zf; }
    gemm128(sm + O_H, wtok, 512, 0, w, l15, lg, acc);
    #pragma unroll
    for (int mt = 0; mt < 8; mt++){
      int e = mt >> 1;
      #pragma unroll
      for (int nt = 0; nt < 2; nt++){
        int colg = (2*w + nt)*16 + l15;
        float ci = sci[e*128 + colg];
        #pragma unroll
        for (int r = 0; r < 4; r++){
          int rowg = mt*16 + lg*4 + r;
          float v = fmaxf(acc[mt][nt][r] + ci, 0.f);
          *(u16*)(sm + O_TOK + soff(rowg, colg, 256, 7)) = f2bf(v);
        }
      }
    }
  }
  __syncthreads();

  // ---- LN1: sTok -> sH
  layernorm128(sm + O_TOK, sm + O_H, ln1_g, ln1_b, tid);
  __syncthreads();

  // ---- attention: 4 chunks of 2 heads
  const int cnt_e = scnt[w];
  for (int hc2 = 0; hc2 < 4; hc2++){
    // qkv GEMM: 6 tiles (q0,q1,k0,k1,v0,v1) round-robined over waves
    for (int tt = w; tt < 6; tt += 4){
      int kind = tt >> 1, sub = tt & 1;
      int wrow = kind*128 + (hc2*2 + sub)*16 + l15;
      f32x4 acc[8];
      #pragma unroll
      for (int mt = 0; mt < 8; mt++) acc[mt] = zf;
      #pragma unroll
      for (int ks = 0; ks < 4; ks++){
        bf8 b = *(const bf8*)(wqkv + wrow*128 + ks*32 + lg*8);
        #pragma unroll
        for (int mt = 0; mt < 8; mt++){
          bf8 a = *(const bf8*)(sm + O_H + soff(mt*16 + l15, ks*32 + lg*8, 256, 7));
          acc[mt] = mfma16(a, b, acc[mt]);
        }
      }
      float bias = qkv_b[wrow];
      #pragma unroll
      for (int mt = 0; mt < 8; mt++){
        #pragma unroll
        for (int r = 0; r < 4; r++){
          int rowg = mt*16 + lg*4 + r;
          u16 hv = f2bf(acc[mt][r] + bias);
          if (kind == 0)      *(u16*)(sm + O_Q   + soff(rowg, sub*16 + l15, 64, 3)) = hv;
          else if (kind == 1) *(u16*)(sm + O_K2L + soff(rowg, sub*16 + l15, 64, 3)) = hv;
          else                *(u16*)(sm + O_VT  + soff(sub*16 + l15, rowg, 256, 7)) = hv;
        }
      }
    }
    __syncthreads();

    // per-edge attention (wave w = edge w), heads 2*hc2, 2*hc2+1
    #pragma unroll
    for (int hh = 0; hh < 2; hh++){
      bf8 z8 = {0,0,0,0,0,0,0,0};
      bf8 qa[2], kb[2];
      #pragma unroll
      for (int mt = 0; mt < 2; mt++)
        qa[mt] = (lg < 2) ? *(const bf8*)(sm + O_Q   + soff(w*32 + mt*16 + l15, hh*16 + lg*8, 64, 3)) : z8;
      #pragma unroll
      for (int nt = 0; nt < 2; nt++)
        kb[nt] = (lg < 2) ? *(const bf8*)(sm + O_K2L + soff(w*32 + nt*16 + l15, hh*16 + lg*8, 64, 3)) : z8;
      f32x4 sc[2][2];
      #pragma unroll
      for (int mt = 0; mt < 2; mt++)
        #pragma unroll
        for (int nt = 0; nt < 2; nt++)
          sc[mt][nt] = mfma16(qa[mt], kb[nt], zf);
      // masked softmax over 32 keys (row spread across 16 lanes x 2 n-frags)
      float pr[2][2][4];
      #pragma unroll
      for (int mt = 0; mt < 2; mt++)
        #pragma unroll
        for (int nt = 0; nt < 2; nt++)
          #pragma unroll
          for (int r = 0; r < 4; r++){
            int colg = nt*16 + l15;
            pr[mt][nt][r] = (colg < cnt_e) ? sc[mt][nt][r]*0.25f : -1e9f;
          }
      char* abase = sm + O_ATT + w*2048;
      #pragma unroll
      for (int mt = 0; mt < 2; mt++)
        #pragma unroll
        for (int r = 0; r < 4; r++){
          float m = fmaxf(pr[mt][0][r], pr[mt][1][r]);
          m = fmaxf(m, __shfl_xor(m, 1)); m = fmaxf(m, __shfl_xor(m, 2));
          m = fmaxf(m, __shfl_xor(m, 4)); m = fmaxf(m, __shfl_xor(m, 8));
          float e0 = __expf(pr[mt][0][r] - m), e1 = __expf(pr[mt][1][r] - m);
          float ss = e0 + e1;
          ss += __shfl_xor(ss, 1); ss += __shfl_xor(ss, 2);
          ss += __shfl_xor(ss, 4); ss += __shfl_xor(ss, 8);
          float inv = 1.f / ss;
          int rowl = mt*16 + lg*4 + r;
          *(u16*)(abase + soff(rowl, l15,      64, 3)) = f2bf(e0*inv);
          *(u16*)(abase + soff(rowl, 16 + l15, 64, 3)) = f2bf(e1*inv);
        }
      // PV
      bf8 vb = *(const bf8*)(sm + O_VT + soff(hh*16 + l15, w*32 + lg*8, 256, 7));
      f32x4 ctx[2] = {zf, zf};
      #pragma unroll
      for (int mt = 0; mt < 2; mt++){
        bf8 pa = *(const bf8*)(abase + soff(mt*16 + l15, lg*8, 64, 3));
        ctx[mt] = mfma16(pa, vb, ctx[mt]);
      }
      int head = hc2*2 + hh;
      #pragma unroll
      for (int mt = 0; mt < 2; mt++)
        #pragma unroll
        for (int r = 0; r < 4; r++){
          int rowg = w*32 + mt*16 + lg*4 + r;
          *(u16*)(sm + O_CTX + soff(rowg, head*16 + l15, 256, 7)) = f2bf(ctx[mt][r]);
        }
    }
    __syncthreads();
  }

  // ---- out projection + residual (RMW sTok)
  {
    f32x4 acc[8][2];
    #pragma unroll
    for (int mt = 0; mt < 8; mt++){ acc[mt][0] = zf; acc[mt][1] = zf; }
    gemm128(sm + O_CTX, wout, 128, 0, w, l15, lg, acc);
    #pragma unroll
    for (int mt = 0; mt < 8; mt++){
      #pragma unroll
      for (int nt = 0; nt < 2; nt++){
        int colg = (2*w + nt)*16 + l15;
        float ob = out_b[colg];
        #pragma unroll
        for (int r = 0; r < 4; r++){
          int rowg = mt*16 + lg*4 + r;
          u16* tp = (u16*)(sm + O_TOK + soff(rowg, colg, 256, 7));
          float v = acc[mt][nt][r] + ob + bf2f(*tp);
          *tp = f2bf(v);
        }
      }
    }
  }
  __syncthreads();

  // ---- LN2: sTok -> sH
  layernorm128(sm + O_TOK, sm + O_H, ln2_g, ln2_b, tid);
  __syncthreads();

  // ---- FF: 4 column chunks of 128; fp32 accumulator carried across chunks
  f32x4 acc2[8][2];
  #pragma unroll
  for (int mt = 0; mt < 8; mt++){ acc2[mt][0] = zf; acc2[mt][1] = zf; }
  for (int c = 0; c < 4; c++){
    f32x4 acc1[8][2];
    #pragma unroll
    for (int mt = 0; mt < 8; mt++){ acc1[mt][0] = zf; acc1[mt][1] = zf; }
    gemm128(sm + O_H, wff1 + (size_t)(c*128)*128, 128, 0, w, l15, lg, acc1);
    #pragma unroll
    for (int mt = 0; mt < 8; mt++){
      #pragma unroll
      for (int nt = 0; nt < 2; nt++){
        int colg = (2*w + nt)*16 + l15;
        float fb = ff1_b[c*128 + colg];
        #pragma unroll
        for (int r = 0; r < 4; r++){
          int rowg = mt*16 + lg*4 + r;
          float vv = acc1[mt][nt][r] + fb;
          vv = 0.5f*vv*(1.f + erff(vv*0.70710678118654752f));   // exact gelu
          *(u16*)(sm + O_CTX + soff(rowg, colg, 256, 7)) = f2bf(vv);
        }
      }
    }
    __syncthreads();
    gemm128(sm + O_CTX, wff2, 512, c*128, w, l15, lg, acc2);
    __syncthreads();
  }

  // ---- final residual + masked mean pool straight from fp32 fragments
  {
    float pool[4][2] = {};
    #pragma unroll
    for (int mt = 0; mt < 8; mt++){
      int e = mt >> 1;
      #pragma unroll
      for (int nt = 0; nt < 2; nt++){
        int colg = (2*w + nt)*16 + l15;
        float fb = ff2_b[colg];
        #pragma unroll
        for (int r = 0; r < 4; r++){
          int rowg = mt*16 + lg*4 + r;
          float tp = bf2f(*(u16*)(sm + O_TOK + soff(rowg, colg, 256, 7)));
          float v = acc2[mt][nt][r] + fb + tp;
          int kk = rowg & 31;
          if (kk < scnt[e]) pool[e][nt] += v;
        }
      }
    }
    #pragma unroll
    for (int e = 0; e < 4; e++){
      #pragma unroll
      for (int nt = 0; nt < 2; nt++){
        float v = pool[e][nt];
        v += __shfl_xor(v, 16);
        v += __shfl_xor(v, 32);
        if (lg == 0){
          int cn = scnt[e];
          float denom = (float)(cn > 0 ? cn : 1);
          xcn_out[(size_t)(t0 + e)*CC + 32*w + nt*16 + l15] = v / denom;
        }
      }
    }
  }
}

// ------------------------------------------------------------------
// K2: edge MLPs, 32 edges per block, 256 blocks
// ------------------------------------------------------------------
DI void gemm32(const char* sA, int astride, int ktiles, const u16* __restrict__ W, int ldk,
               int w, int l15, int lg, f32x4 (&acc)[2][4]){
  for (int ks = 0; ks < ktiles; ks++){
    bf8 a0 = *(const bf8*)(sA + soff(0*16 + l15, ks*32 + lg*8, astride, 7));
    bf8 a1 = *(const bf8*)(sA + soff(1*16 + l15, ks*32 + lg*8, astride, 7));
    #pragma unroll
    for (int nt = 0; nt < 4; nt++){
      int wrow = (4*w + nt)*16 + l15;
      bf8 b = *(const bf8*)(W + wrow*ldk + ks*32 + lg*8);
      acc[0][nt] = mfma16(a0, b, acc[0][nt]);
      acc[1][nt] = mfma16(a1, b, acc[1][nt]);
    }
  }
}

DI void store_h(char* dst, f32x4 (&acc)[2][4], const float* __restrict__ bias, bool relu,
                int w, int l15, int lg){
  #pragma unroll
  for (int mt = 0; mt < 2; mt++)
    #pragma unroll
    for (int nt = 0; nt < 4; nt++){
      int colg = (4*w + nt)*16 + l15;
      float bb = bias[colg];
      #pragma unroll
      for (int r = 0; r < 4; r++){
        int rowg = mt*16 + lg*4 + r;
        float v = acc[mt][nt][r] + bb;
        if (relu) v = fmaxf(v, 0.f);
        *(u16*)(dst + soff(rowg, colg, 512, 7)) = f2bf(v);
      }
    }
}

__global__ __launch_bounds__(256, 1)
void k2_mlp(const float* __restrict__ xcn, const float* __restrict__ xij,
            const u16* __restrict__ wbf,
            const float* __restrict__ xcn_b1, const float* __restrict__ xcn_b2,
            const float* __restrict__ xcn_b3, const float* __restrict__ xij_b1,
            const float* __restrict__ xij_b2, const float* __restrict__ lin_b1,
            const float* __restrict__ lin_w2, const float* __restrict__ lin_b2,
            const float* __restrict__ beta_p, float* __restrict__ out)
{
  __shared__ __align__(16) char sm[98304];
  const int O_A = 0, O_X = 8192, O_H1 = 16384, O_H2 = 32768, O_X1 = 49152, O_Z = 65536, O_Z2 = 81920;
  const u16* w1  = wbf + 262144;   // [256][128]
  const u16* w2  = wbf + 294912;   // [256][256]
  const u16* w3  = wbf + 360448;   // [256][256]
  const u16* xw1 = wbf + 425984;   // [256][128]
  const u16* xw2 = wbf + 458752;   // [256][256]
  const u16* lw1 = wbf + 524288;   // [256][256]
  const int tid = threadIdx.x;
  const int w = tid >> 6, l = tid & 63, l15 = l & 15, lg = l >> 4;
  const int t0 = blockIdx.x * 32;
  const f32x4 zf = {0.f,0.f,0.f,0.f};

  // stage xcn, xij as bf16 (swizzled, stride 256)
  {
    int r = tid >> 3, ci0 = (tid & 7) * 16;
    const float4* ps = (const float4*)(xcn + (size_t)(t0 + r)*CC + ci0);
    const float4* qs = (const float4*)(xij + (size_t)(t0 + r)*CC + ci0);
    #pragma unroll
    for (int h = 0; h < 2; h++){
      float4 a = ps[2*h], b = ps[2*h+1];
      bf8 v;
      v[0]=(short)f2bf(a.x); v[1]=(short)f2bf(a.y); v[2]=(short)f2bf(a.z); v[3]=(short)f2bf(a.w);
      v[4]=(short)f2bf(b.x); v[5]=(short)f2bf(b.y); v[6]=(short)f2bf(b.z); v[7]=(short)f2bf(b.w);
      *(bf8*)(sm + O_A + soff(r, ci0 + h*8, 256, 7)) = v;
      float4 cq = qs[2*h], dq = qs[2*h+1];
      bf8 u;
      u[0]=(short)f2bf(cq.x); u[1]=(short)f2bf(cq.y); u[2]=(short)f2bf(cq.z); u[3]=(short)f2bf(cq.w);
      u[4]=(short)f2bf(dq.x); u[5]=(short)f2bf(dq.y); u[6]=(short)f2bf(dq.z); u[7]=(short)f2bf(dq.w);
      *(bf8*)(sm + O_X + soff(r, ci0 + h*8, 256, 7)) = u;
    }
  }
  __syncthreads();

  f32x4 acc[2][4];
  // L1: relu(xcn @ w1^T + b1)
  #pragma unroll
  for (int mt=0;mt<2;mt++) for (int nt=0;nt<4;nt++) acc[mt][nt] = zf;
  gemm32(sm + O_A, 256, 4, w1, 128, w, l15, lg, acc);
  store_h(sm + O_H1, acc, xcn_b1, true, w, l15, lg);
  __syncthreads();
  // L2: relu(h1 @ w2^T + b2)
  #pragma unroll
  for (int mt=0;mt<2;mt++) for (int nt=0;nt<4;nt++) acc[mt][nt] = zf;
  gemm32(sm + O_H1, 512, 8, w2, 256, w, l15, lg, acc);
  store_h(sm + O_H2, acc, xcn_b2, true, w, l15, lg);
  __syncthreads();
  // L3 (no act) kept in regs; X1 in parallel region
  f32x4 hc[2][4];
  #pragma unroll
  for (int mt=0;mt<2;mt++) for (int nt=0;nt<4;nt++) hc[mt][nt] = zf;
  gemm32(sm + O_H2, 512, 8, w3, 256, w, l15, lg, hc);
  #pragma unroll
  for (int mt=0;mt<2;mt++) for (int nt=0;nt<4;nt++) acc[mt][nt] = zf;
  gemm32(sm + O_X, 256, 4, xw1, 128, w, l15, lg, acc);
  store_h(sm + O_X1, acc, xij_b1, true, w, l15, lg);
  __syncthreads();
  // X2 (no act)
  f32x4 x2[2][4];
  #pragma unroll
  for (int mt=0;mt<2;mt++) for (int nt=0;nt<4;nt++) x2[mt][nt] = zf;
  gemm32(sm + O_X1, 512, 8, xw2, 256, w, l15, lg, x2);
  // combine: z0 = (hc + b3)*beta + (x2 + xb2)  -> sZ
  {
    float beta = beta_p[0];
    #pragma unroll
    for (int mt = 0; mt < 2; mt++)
      #pragma unroll
      for (int nt = 0; nt < 4; nt++){
        int colg = (4*w + nt)*16 + l15;
        float b3v = xcn_b3[colg], xbv = xij_b2[colg];
        #pragma unroll
        for (int r = 0; r < 4; r++){
          int rowg = mt*16 + lg*4 + r;
          float v = (hc[mt][nt][r] + b3v)*beta + (x2[mt][nt][r] + xbv);
          *(u16*)(sm + O_Z + soff(rowg, colg, 512, 7)) = f2bf(v);
        }
      }
  }
  __syncthreads();
  // Z: relu(z0 @ lin_w1^T + lin_b1)
  #pragma unroll
  for (int mt=0;mt<2;mt++) for (int nt=0;nt<4;nt++) acc[mt][nt] = zf;
  gemm32(sm + O_Z, 512, 8, lw1, 256, w, l15, lg, acc);
  store_h(sm + O_Z2, acc, lin_b1, true, w, l15, lg);
  __syncthreads();
  // final dot with lin_w2 (8 lanes per edge)
  {
    int e = tid >> 3, li = tid & 7;
    float s = 0.f;
    #pragma unroll
    for (int i = 0; i < 32; i++){
      int c = li*32 + i;
      s += bf2f(*(u16*)(sm + O_Z2 + soff(e, c, 512, 7))) * lin_w2[c];
    }
    s += __shfl_xor(s, 1); s += __shfl_xor(s, 2); s += __shfl_xor(s, 4);
    if (li == 0) out[t0 + e] = s + lin_b2[0];
  }
}

// ------------------------------------------------------------------
extern "C" void kernel_launch(void* const* d_in, const int* in_sizes, int n_in,
                              void* d_out, int out_size, void* d_ws, size_t ws_size,
                              hipStream_t stream){
  (void)in_sizes; (void)n_in; (void)out_size; (void)ws_size;
  const float* x        = (const float*)d_in[0];
  const int*   tar_ei   = (const int*)  d_in[1];
  const int*   cn_cols  = (const int*)  d_in[2];
  const int*   cn_cnt   = (const int*)  d_in[3];
  const float* beta     = (const float*)d_in[4];
  const float* tok_w    = (const float*)d_in[5];
  const float* tok_b    = (const float*)d_in[6];
  const float* ln1_g    = (const float*)d_in[7];
  const float* ln1_b    = (const float*)d_in[8];
  const float* qkv_w    = (const float*)d_in[9];
  const float* qkv_b    = (const float*)d_in[10];
  const float* out_w    = (const float*)d_in[11];
  const float* out_b    = (const float*)d_in[12];
  const float* ln2_g    = (const float*)d_in[13];
  const float* ln2_b    = (const float*)d_in[14];
  const float* ff1_w    = (const float*)d_in[15];
  const float* ff1_b    = (const float*)d_in[16];
  const float* ff2_w    = (const float*)d_in[17];
  const float* ff2_b    = (const float*)d_in[18];
  const float* xcn_w1   = (const float*)d_in[19];
  const float* xcn_b1   = (const float*)d_in[20];
  const float* xcn_w2   = (const float*)d_in[21];
  const float* xcn_b2   = (const float*)d_in[22];
  const float* xcn_w3   = (const float*)d_in[23];
  const float* xcn_b3   = (const float*)d_in[24];
  const float* xij_w1   = (const float*)d_in[25];
  const float* xij_b1   = (const float*)d_in[26];
  const float* xij_w2   = (const float*)d_in[27];
  const float* xij_b2   = (const float*)d_in[28];
  const float* lin_w1   = (const float*)d_in[29];
  const float* lin_b1   = (const float*)d_in[30];
  const float* lin_w2   = (const float*)d_in[31];
  const float* lin_b2   = (const float*)d_in[32];

  u16*   wbf = (u16*)d_ws;
  float* xcn = (float*)((char*)d_ws + (size_t)(2u<<20));   // 4 MB
  float* xij = (float*)((char*)d_ws + (size_t)(6u<<20));   // 4 MB

  WP wp;
  wp.p[0]=tok_w; wp.p[1]=qkv_w; wp.p[2]=out_w; wp.p[3]=ff1_w; wp.p[4]=ff2_w;
  wp.p[5]=xcn_w1; wp.p[6]=xcn_w2; wp.p[7]=xcn_w3; wp.p[8]=xij_w1; wp.p[9]=xij_w2;
  wp.p[10]=lin_w1; wp.p[11]=lin_w2;

  k0_convert<<<dim3(2305), dim3(256), 0, stream>>>(wp, wbf);
  k1_fused<<<dim3(TT/4), dim3(256), 0, stream>>>(
      x, tar_ei, cn_cols, cn_cnt, tok_b, ln1_g, ln1_b, qkv_b, out_b,
      ln2_g, ln2_b, ff1_b, ff2_b, wbf, xcn, xij);
  k2_mlp<<<dim3(TT/32), dim3(256), 0, stream>>>(
      xcn, xij, wbf, xcn_b1, xcn_b2, xcn_b3, xij_b1, xij_b2,
      lin_b1, lin_w2, lin_b2, beta, (float*)d_out);
}

// Round 2
// 830.701 us; speedup vs baseline: 1.1320x; 1.1320x over previous
//
#include <hip/hip_runtime.h>
#include <hip/hip_bf16.h>
#include <math.h>

#define DI __device__ __forceinline__

typedef float  f32x4 __attribute__((ext_vector_type(4)));
typedef short  bf8   __attribute__((ext_vector_type(8)));
typedef unsigned short u16;

static constexpr int TT = 8192;   // T edges
static constexpr int KK = 32;     // CN tokens per edge
static constexpr int CC = 128;    // channels

DI u16 f2bf(float x){ union{float f; unsigned u;} v; v.f = x; unsigned r = v.u + 0x7FFFu + ((v.u>>16)&1u); return (u16)(r>>16); }
DI float bf2f(u16 b){ union{unsigned u; float f;} v; v.u = ((unsigned)b)<<16; return v.f; }
DI unsigned pk2(float a, float b){ return (unsigned)f2bf(a) | ((unsigned)f2bf(b)<<16); }
DI f32x4 mfma16(bf8 a, bf8 b, f32x4 c){ return __builtin_amdgcn_mfma_f32_16x16x32_bf16(a, b, c, 0, 0, 0); }
// swizzled LDS byte offset: row-major [*][stride bytes], xor row bits into 16B-slot bits
DI int soff(int r, int c, int stride, int mask){ return r*stride + ((c*2) ^ ((r&mask)<<4)); }

// ------------------------------------------------------------------
// K0: convert the 12 weight matrices fp32 -> bf16 blob in ws
// ------------------------------------------------------------------
struct WP { const float* p[12]; };

__global__ void k0_convert(WP wp, u16* __restrict__ dst){
  const int sz[12] = {65536,49152,16384,65536,65536,32768,65536,65536,32768,65536,65536,256};
  int gid = blockIdx.x*256 + threadIdx.x;   // total 590080 = 2305*256
  int off = 0;
  #pragma unroll
  for (int s = 0; s < 12; s++){
    if (gid < off + sz[s]){ dst[gid] = f2bf(wp.p[s][gid - off]); return; }
    off += sz[s];
  }
}

// ------------------------------------------------------------------
// K1: fused gather + tokenlin + transformer layer + masked mean pool
// 1 block = 2 edges = 64 token rows, 256 threads (4 waves).
// wave w owns output columns [32w, 32w+32) for GEMMs (n-split);
// attention: wave w -> edge (w>>1), head-sub (w&1).
// LDS ~52.6 KB -> 3 blocks/CU.
// ------------------------------------------------------------------
#define O_TOK 0        // [64][128] bf16 sw(256,7)  16K  residual
#define O_H   16384    // [64][128] bf16 sw(256,7)  16K  ln out / xw staging
#define O_RG  32768    // 20K multi-use region:
                       //  phase0: cols int[64] @+0, xibuf u32[2][3][64] @+512
                       //  attn:   Q[64][32] sw(64,3) @+0, K @+4096,
                       //          VT[32][64] sw(128,7) @+8192, ATT 4x2K @+12288
                       //  then:   CTX [64][128] sw(256,7) @+0 (16K)
                       //  then:   gelu chunk [64][128] sw(256,7) @+0 (16K)
#define O_CNT 53248    // int[2]
#define LDS_K1 53264

DI void layernorm64(const char* src, char* dst, const float* __restrict__ g,
                    const float* __restrict__ bta, int tid){
  int r = tid >> 2, q = tid & 3;
  float v[32]; float s = 0.f, sq = 0.f;
  #pragma unroll
  for (int i = 0; i < 4; i++){
    bf8 h8 = *(const bf8*)(src + soff(r, q*32 + i*8, 256, 7));
    #pragma unroll
    for (int j = 0; j < 8; j++){ float f = bf2f((u16)h8[j]); v[i*8+j] = f; s += f; sq += f*f; }
  }
  s  += __shfl_xor(s, 1);  s  += __shfl_xor(s, 2);
  sq += __shfl_xor(sq, 1); sq += __shfl_xor(sq, 2);
  float mu = s * (1.f/128.f);
  float rstd = rsqrtf(sq*(1.f/128.f) - mu*mu + 1e-5f);
  #pragma unroll
  for (int i = 0; i < 4; i++){
    bf8 o;
    #pragma unroll
    for (int j = 0; j < 8; j++){
      int c = q*32 + i*8 + j;
      o[j] = (short)f2bf((v[i*8+j] - mu)*rstd*g[c] + bta[c]);
    }
    *(bf8*)(dst + soff(r, q*32 + i*8, 256, 7)) = o;
  }
}

// n-split GEMM: [64 rows x 128 cols(4 waves x 32)] += LDS_A[64][128] * W^T chunk
DI void gemm64(const char* sA, const u16* __restrict__ W, int ldk, int koff,
               int w, int l15, int lg, f32x4 (&acc)[4][2]){
  #pragma unroll
  for (int ks = 0; ks < 4; ks++){
    bf8 b0 = *(const bf8*)(W + ((2*w+0)*16 + l15)*ldk + koff + ks*32 + lg*8);
    bf8 b1 = *(const bf8*)(W + ((2*w+1)*16 + l15)*ldk + koff + ks*32 + lg*8);
    #pragma unroll
    for (int mt = 0; mt < 4; mt++){
      bf8 a = *(const bf8*)(sA + soff(mt*16 + l15, ks*32 + lg*8, 256, 7));
      acc[mt][0] = mfma16(a, b0, acc[mt][0]);
      acc[mt][1] = mfma16(a, b1, acc[mt][1]);
    }
  }
}

__global__ __launch_bounds__(256, 3)
void k1_fused(const float* __restrict__ x, const int* __restrict__ tar_ei,
              const int* __restrict__ cn_cols, const int* __restrict__ cn_counts,
              const float* __restrict__ tok_b,
              const float* __restrict__ ln1_g, const float* __restrict__ ln1_b,
              const float* __restrict__ qkv_b, const float* __restrict__ out_b,
              const float* __restrict__ ln2_g, const float* __restrict__ ln2_b,
              const float* __restrict__ ff1_b, const float* __restrict__ ff2_b,
              const u16* __restrict__ wbf,
              float* __restrict__ xcn_out, float* __restrict__ xij_out)
{
  __shared__ __align__(16) char sm[LDS_K1];
  const int tid = threadIdx.x;
  const int w = tid >> 6, l = tid & 63, l15 = l & 15, lg = l >> 4;
  const int t0 = blockIdx.x * 2;

  const u16* wtok = wbf;            // [128][512]
  const u16* wqkv = wbf + 65536;    // [384][128]
  const u16* wout = wbf + 114688;   // [128][128]
  const u16* wff1 = wbf + 131072;   // [512][128]
  const u16* wff2 = wbf + 196608;   // [128][512]

  int* scnt  = (int*)(sm + O_CNT);
  int* scols = (int*)(sm + O_RG);
  const f32x4 zf = {0.f, 0.f, 0.f, 0.f};

  // ---- phase 0a: indices
  if (tid < 2)  scnt[tid]  = cn_counts[t0 + tid];
  if (tid < 64) scols[tid] = cn_cols[(t0 + (tid >> 5))*KK + (tid & 31)];
  __syncthreads();

  // ---- phase 0b: gather xw -> sH (bf16, swizzled). 4 threads per row.
  {
    int r = tid >> 2, q = tid & 3;
    const float4* xs = (const float4*)(x + (size_t)scols[r]*CC) + q*8;
    #pragma unroll
    for (int i = 0; i < 4; i++){
      float4 a = xs[2*i], b = xs[2*i+1];
      bf8 v;
      v[0]=(short)f2bf(a.x); v[1]=(short)f2bf(a.y); v[2]=(short)f2bf(a.z); v[3]=(short)f2bf(a.w);
      v[4]=(short)f2bf(b.x); v[5]=(short)f2bf(b.y); v[6]=(short)f2bf(b.z); v[7]=(short)f2bf(b.w);
      *(bf8*)(sm + O_H + soff(r, q*32 + i*8, 256, 7)) = v;
    }
  }
  // ---- phase 0c: stage xi/xj/xi*xj broadcast rows + write xij to ws (waves 0-1)
  if (w < 2){
    int e = w, c0 = l*2;
    int ti = tar_ei[t0 + e], tj = tar_ei[TT + t0 + e];
    float vix = x[(size_t)ti*CC + c0], viy = x[(size_t)ti*CC + c0 + 1];
    float vjx = x[(size_t)tj*CC + c0], vjy = x[(size_t)tj*CC + c0 + 1];
    float px = vix*vjx, py = viy*vjy;
    xij_out[(size_t)(t0+e)*CC + c0]     = px;
    xij_out[(size_t)(t0+e)*CC + c0 + 1] = py;
    unsigned* xb = (unsigned*)(sm + O_RG + 512) + e*192;   // [3][64] u32
    xb[l]       = pk2(vix, viy);
    xb[64 + l]  = pk2(vjx, vjy);
    xb[128 + l] = pk2(px, py);
  }
  __syncthreads();

  // ---- phase 0e: tokenlin GEMM, K=512 in 4 chunks.
  // chunk 0 = gathered xw (H); chunks 1-3 = per-edge broadcast rows (xi,xj,xi*xj).
  {
    f32x4 acc[4][2];
    #pragma unroll
    for (int mt = 0; mt < 4; mt++){ acc[mt][0] = zf; acc[mt][1] = zf; }
    gemm64(sm + O_H, wtok, 512, 0, w, l15, lg, acc);
    #pragma unroll
    for (int c = 1; c < 4; c++){
      #pragma unroll
      for (int ks = 0; ks < 4; ks++){
        bf8 b0 = *(const bf8*)(wtok + ((2*w+0)*16 + l15)*512 + c*128 + ks*32 + lg*8);
        bf8 b1 = *(const bf8*)(wtok + ((2*w+1)*16 + l15)*512 + c*128 + ks*32 + lg*8);
        #pragma unroll
        for (int mt = 0; mt < 4; mt++){
          int e = mt >> 1;
          bf8 a = *(const bf8*)(sm + O_RG + 512 + (e*192 + (c-1)*64)*4 + (ks*32 + lg*8)*2);
          acc[mt][0] = mfma16(a, b0, acc[mt][0]);
          acc[mt][1] = mfma16(a, b1, acc[mt][1]);
        }
      }
    }
    #pragma unroll
    for (int mt = 0; mt < 4; mt++){
      #pragma unroll
      for (int nt = 0; nt < 2; nt++){
        int colg = (2*w + nt)*16 + l15;
        float tb = tok_b[colg];
        #pragma unroll
        for (int r = 0; r < 4; r++){
          int rowg = mt*16 + lg*4 + r;
          float v = fmaxf(acc[mt][nt][r] + tb, 0.f);
          *(u16*)(sm + O_TOK + soff(rowg, colg, 256, 7)) = f2bf(v);
        }
      }
    }
  }
  __syncthreads();

  // ---- LN1: sTok -> sH
  layernorm64(sm + O_TOK, sm + O_H, ln1_g, ln1_b, tid);
  __syncthreads();

  // ---- attention: 4 chunks of 2 heads; ctx accumulated in packed regs
  unsigned pk[4][4];
  const int e_w = w >> 1, hh_w = w & 1;
  const int cnt_e = scnt[e_w];
  char* const sQ  = sm + O_RG;
  char* const sK  = sm + O_RG + 4096;
  char* const sVT = sm + O_RG + 8192;
  char* const sAT = sm + O_RG + 12288 + w*2048;
  #pragma unroll
  for (int hc2 = 0; hc2 < 4; hc2++){
    // qkv: 6 tiles (q/k/v x 2 heads), round-robin over 4 waves
    for (int tt = w; tt < 6; tt += 4){
      int kind = tt >> 1, sub = tt & 1;
      int wrow = kind*128 + (hc2*2 + sub)*16 + l15;
      f32x4 acc[4];
      #pragma unroll
      for (int mt = 0; mt < 4; mt++) acc[mt] = zf;
      #pragma unroll
      for (int ks = 0; ks < 4; ks++){
        bf8 b = *(const bf8*)(wqkv + wrow*128 + ks*32 + lg*8);
        #pragma unroll
        for (int mt = 0; mt < 4; mt++){
          bf8 a = *(const bf8*)(sm + O_H + soff(mt*16 + l15, ks*32 + lg*8, 256, 7));
          acc[mt] = mfma16(a, b, acc[mt]);
        }
      }
      float bias = qkv_b[wrow];
      #pragma unroll
      for (int mt = 0; mt < 4; mt++){
        #pragma unroll
        for (int r = 0; r < 4; r++){
          int rowg = mt*16 + lg*4 + r;
          u16 hv = f2bf(acc[mt][r] + bias);
          if (kind == 0)      *(u16*)(sQ  + soff(rowg, sub*16 + l15, 64, 3)) = hv;
          else if (kind == 1) *(u16*)(sK  + soff(rowg, sub*16 + l15, 64, 3)) = hv;
          else                *(u16*)(sVT + soff(sub*16 + l15, rowg, 128, 7)) = hv;
        }
      }
    }
    __syncthreads();

    // per-wave attention: edge e_w, head hh_w of this chunk
    {
      bf8 z8 = {0,0,0,0,0,0,0,0};
      bf8 qa[2], kb[2];
      #pragma unroll
      for (int mt = 0; mt < 2; mt++)
        qa[mt] = (lg < 2) ? *(const bf8*)(sQ + soff(e_w*32 + mt*16 + l15, hh_w*16 + lg*8, 64, 3)) : z8;
      #pragma unroll
      for (int nt = 0; nt < 2; nt++)
        kb[nt] = (lg < 2) ? *(const bf8*)(sK + soff(e_w*32 + nt*16 + l15, hh_w*16 + lg*8, 64, 3)) : z8;
      f32x4 sc[2][2];
      #pragma unroll
      for (int mt = 0; mt < 2; mt++)
        #pragma unroll
        for (int nt = 0; nt < 2; nt++)
          sc[mt][nt] = mfma16(qa[mt], kb[nt], zf);
      float pr[2][2][4];
      #pragma unroll
      for (int mt = 0; mt < 2; mt++)
        #pragma unroll
        for (int nt = 0; nt < 2; nt++)
          #pragma unroll
          for (int r = 0; r < 4; r++)
            pr[mt][nt][r] = (nt*16 + l15 < cnt_e) ? sc[mt][nt][r]*0.25f : -1e9f;
      #pragma unroll
      for (int mt = 0; mt < 2; mt++)
        #pragma unroll
        for (int r = 0; r < 4; r++){
          float m = fmaxf(pr[mt][0][r], pr[mt][1][r]);
          m = fmaxf(m, __shfl_xor(m, 1)); m = fmaxf(m, __shfl_xor(m, 2));
          m = fmaxf(m, __shfl_xor(m, 4)); m = fmaxf(m, __shfl_xor(m, 8));
          float e0 = __expf(pr[mt][0][r] - m), e1 = __expf(pr[mt][1][r] - m);
          float ss = e0 + e1;
          ss += __shfl_xor(ss, 1); ss += __shfl_xor(ss, 2);
          ss += __shfl_xor(ss, 4); ss += __shfl_xor(ss, 8);
          float inv = 1.f / ss;
          int rowl = mt*16 + lg*4 + r;
          *(u16*)(sAT + soff(rowl, l15,      64, 3)) = f2bf(e0*inv);
          *(u16*)(sAT + soff(rowl, 16 + l15, 64, 3)) = f2bf(e1*inv);
        }
      // PV: ctx[32 rows][16 dh] for this head
      bf8 vb = *(const bf8*)(sVT + soff(hh_w*16 + l15, e_w*32 + lg*8, 128, 7));
      #pragma unroll
      for (int mtp = 0; mtp < 2; mtp++){
        bf8 pa = *(const bf8*)(sAT + soff(mtp*16 + l15, lg*8, 64, 3));
        f32x4 cx = mfma16(pa, vb, zf);
        pk[hc2][mtp*2+0] = pk2(cx[0], cx[1]);
        pk[hc2][mtp*2+1] = pk2(cx[2], cx[3]);
      }
    }
    __syncthreads();
  }

  // ---- write ctx fragments to CTX region (overlays Q/K/VT/ATT)
  #pragma unroll
  for (int hc = 0; hc < 4; hc++){
    int head = hc*2 + hh_w;
    #pragma unroll
    for (int mtp = 0; mtp < 2; mtp++)
      #pragma unroll
      for (int i = 0; i < 2; i++){
        unsigned pv = pk[hc][mtp*2+i];
        int rowg = e_w*32 + mtp*16 + lg*4 + i*2;
        *(u16*)(sm + O_RG + soff(rowg,     head*16 + l15, 256, 7)) = (u16)(pv & 0xffffu);
        *(u16*)(sm + O_RG + soff(rowg + 1, head*16 + l15, 256, 7)) = (u16)(pv >> 16);
      }
  }
  __syncthreads();

  // ---- out projection + residual (RMW sTok)
  {
    f32x4 acc[4][2];
    #pragma unroll
    for (int mt = 0; mt < 4; mt++){ acc[mt][0] = zf; acc[mt][1] = zf; }
    gemm64(sm + O_RG, wout, 128, 0, w, l15, lg, acc);
    #pragma unroll
    for (int mt = 0; mt < 4; mt++){
      #pragma unroll
      for (int nt = 0; nt < 2; nt++){
        int colg = (2*w + nt)*16 + l15;
        float ob = out_b[colg];
        #pragma unroll
        for (int r = 0; r < 4; r++){
          int rowg = mt*16 + lg*4 + r;
          u16* tp = (u16*)(sm + O_TOK + soff(rowg, colg, 256, 7));
          float v = acc[mt][nt][r] + ob + bf2f(*tp);
          *tp = f2bf(v);
        }
      }
    }
  }
  __syncthreads();

  // ---- LN2: sTok -> sH
  layernorm64(sm + O_TOK, sm + O_H, ln2_g, ln2_b, tid);
  __syncthreads();

  // ---- FF: 4 column chunks of 128; fp32 accumulator carried across chunks
  f32x4 acc2[4][2];
  #pragma unroll
  for (int mt = 0; mt < 4; mt++){ acc2[mt][0] = zf; acc2[mt][1] = zf; }
  for (int c = 0; c < 4; c++){
    f32x4 acc1[4][2];
    #pragma unroll
    for (int mt = 0; mt < 4; mt++){ acc1[mt][0] = zf; acc1[mt][1] = zf; }
    gemm64(sm + O_H, wff1 + (size_t)(c*128)*128, 128, 0, w, l15, lg, acc1);
    #pragma unroll
    for (int mt = 0; mt < 4; mt++){
      #pragma unroll
      for (int nt = 0; nt < 2; nt++){
        int colg = (2*w + nt)*16 + l15;
        float fb = ff1_b[c*128 + colg];
        #pragma unroll
        for (int r = 0; r < 4; r++){
          int rowg = mt*16 + lg*4 + r;
          float vv = acc1[mt][nt][r] + fb;
          vv = 0.5f*vv*(1.f + erff(vv*0.70710678118654752f));   // exact gelu
          *(u16*)(sm + O_RG + soff(rowg, colg, 256, 7)) = f2bf(vv);
        }
      }
    }
    __syncthreads();
    gemm64(sm + O_RG, wff2, 512, c*128, w, l15, lg, acc2);
    __syncthreads();
  }

  // ---- final residual + masked mean pool straight from fp32 fragments
  {
    float pool[2][2] = {};
    #pragma unroll
    for (int mt = 0; mt < 4; mt++){
      int e = mt >> 1;
      #pragma unroll
      for (int nt = 0; nt < 2; nt++){
        int colg = (2*w + nt)*16 + l15;
        float fb = ff2_b[colg];
        #pragma unroll
        for (int r = 0; r < 4; r++){
          int rowg = mt*16 + lg*4 + r;
          float tp = bf2f(*(u16*)(sm + O_TOK + soff(rowg, colg, 256, 7)));
          float v = acc2[mt][nt][r] + fb + tp;
          if ((rowg & 31) < scnt[e]) pool[e][nt] += v;
        }
      }
    }
    #pragma unroll
    for (int e = 0; e < 2; e++){
      #pragma unroll
      for (int nt = 0; nt < 2; nt++){
        float v = pool[e][nt];
        v += __shfl_xor(v, 16);
        v += __shfl_xor(v, 32);
        if (lg == 0){
          int cn = scnt[e];
          float denom = (float)(cn > 0 ? cn : 1);
          xcn_out[(size_t)(t0 + e)*CC + 32*w + nt*16 + l15] = v / denom;
        }
      }
    }
  }
}

// ------------------------------------------------------------------
// K2: edge MLPs, 32 edges per block, 256 blocks. 4 aliased buffers, 48 KB.
// ------------------------------------------------------------------
DI void gemm32(const char* sA, int astride, int ktiles, const u16* __restrict__ W, int ldk,
               int w, int l15, int lg, f32x4 (&acc)[2][4]){
  for (int ks = 0; ks < ktiles; ks++){
    bf8 a0 = *(const bf8*)(sA + soff(0*16 + l15, ks*32 + lg*8, astride, 7));
    bf8 a1 = *(const bf8*)(sA + soff(1*16 + l15, ks*32 + lg*8, astride, 7));
    #pragma unroll
    for (int nt = 0; nt < 4; nt++){
      int wrow = (4*w + nt)*16 + l15;
      bf8 b = *(const bf8*)(W + wrow*ldk + ks*32 + lg*8);
      acc[0][nt] = mfma16(a0, b, acc[0][nt]);
      acc[1][nt] = mfma16(a1, b, acc[1][nt]);
    }
  }
}

DI void store_h(char* dst, f32x4 (&acc)[2][4], const float* __restrict__ bias, bool relu,
                int w, int l15, int lg){
  #pragma unroll
  for (int mt = 0; mt < 2; mt++)
    #pragma unroll
    for (int nt = 0; nt < 4; nt++){
      int colg = (4*w + nt)*16 + l15;
      float bb = bias[colg];
      #pragma unroll
      for (int r = 0; r < 4; r++){
        int rowg = mt*16 + lg*4 + r;
        float v = acc[mt][nt][r] + bb;
        if (relu) v = fmaxf(v, 0.f);
        *(u16*)(dst + soff(rowg, colg, 512, 7)) = f2bf(v);
      }
    }
}

__global__ __launch_bounds__(256, 3)
void k2_mlp(const float* __restrict__ xcn, const float* __restrict__ xij,
            const u16* __restrict__ wbf,
            const float* __restrict__ xcn_b1, const float* __restrict__ xcn_b2,
            const float* __restrict__ xcn_b3, const float* __restrict__ xij_b1,
            const float* __restrict__ xij_b2, const float* __restrict__ lin_b1,
            const float* __restrict__ lin_w2, const float* __restrict__ lin_b2,
            const float* __restrict__ beta_p, float* __restrict__ out)
{
  __shared__ __align__(16) char sm[49152];
  const int O_A = 0, O_X = 8192, O_B1 = 16384, O_B2 = 32768;
  const u16* w1  = wbf + 262144;   // [256][128]
  const u16* w2  = wbf + 294912;   // [256][256]
  const u16* w3  = wbf + 360448;   // [256][256]
  const u16* xw1 = wbf + 425984;   // [256][128]
  const u16* xw2 = wbf + 458752;   // [256][256]
  const u16* lw1 = wbf + 524288;   // [256][256]
  const int tid = threadIdx.x;
  const int w = tid >> 6, l15 = tid & 15, lg = (tid & 63) >> 4;
  const int t0 = blockIdx.x * 32;
  const f32x4 zf = {0.f,0.f,0.f,0.f};

  // stage xcn, xij as bf16 (swizzled, stride 256)
  {
    int r = tid >> 3, ci0 = (tid & 7) * 16;
    const float4* ps = (const float4*)(xcn + (size_t)(t0 + r)*CC + ci0);
    const float4* qs = (const float4*)(xij + (size_t)(t0 + r)*CC + ci0);
    #pragma unroll
    for (int h = 0; h < 2; h++){
      float4 a = ps[2*h], b = ps[2*h+1];
      bf8 v;
      v[0]=(short)f2bf(a.x); v[1]=(short)f2bf(a.y); v[2]=(short)f2bf(a.z); v[3]=(short)f2bf(a.w);
      v[4]=(short)f2bf(b.x); v[5]=(short)f2bf(b.y); v[6]=(short)f2bf(b.z); v[7]=(short)f2bf(b.w);
      *(bf8*)(sm + O_A + soff(r, ci0 + h*8, 256, 7)) = v;
      float4 cq = qs[2*h], dq = qs[2*h+1];
      bf8 u;
      u[0]=(short)f2bf(cq.x); u[1]=(short)f2bf(cq.y); u[2]=(short)f2bf(cq.z); u[3]=(short)f2bf(cq.w);
      u[4]=(short)f2bf(dq.x); u[5]=(short)f2bf(dq.y); u[6]=(short)f2bf(dq.z); u[7]=(short)f2bf(dq.w);
      *(bf8*)(sm + O_X + soff(r, ci0 + h*8, 256, 7)) = u;
    }
  }
  __syncthreads();

  f32x4 acc[2][4];
  // L1: relu(xcn @ w1^T + b1) : A -> B1
  #pragma unroll
  for (int mt=0;mt<2;mt++) for (int nt=0;nt<4;nt++) acc[mt][nt] = zf;
  gemm32(sm + O_A, 256, 4, w1, 128, w, l15, lg, acc);
  store_h(sm + O_B1, acc, xcn_b1, true, w, l15, lg);
  __syncthreads();
  // L2: relu(h1 @ w2^T + b2) : B1 -> B2
  #pragma unroll
  for (int mt=0;mt<2;mt++) for (int nt=0;nt<4;nt++) acc[mt][nt] = zf;
  gemm32(sm + O_B1, 512, 8, w2, 256, w, l15, lg, acc);
  store_h(sm + O_B2, acc, xcn_b2, true, w, l15, lg);
  __syncthreads();
  // L3 (no act) B2 -> regs; X1: X -> B1 (B1 free after L2 barrier)
  f32x4 hc[2][4];
  #pragma unroll
  for (int mt=0;mt<2;mt++) for (int nt=0;nt<4;nt++) hc[mt][nt] = zf;
  gemm32(sm + O_B2, 512, 8, w3, 256, w, l15, lg, hc);
  #pragma unroll
  for (int mt=0;mt<2;mt++) for (int nt=0;nt<4;nt++) acc[mt][nt] = zf;
  gemm32(sm + O_X, 256, 4, xw1, 128, w, l15, lg, acc);
  store_h(sm + O_B1, acc, xij_b1, true, w, l15, lg);
  __syncthreads();
  // X2 (no act): B1 -> regs; combine -> B2 (all waves past L3 reads)
  f32x4 x2[2][4];
  #pragma unroll
  for (int mt=0;mt<2;mt++) for (int nt=0;nt<4;nt++) x2[mt][nt] = zf;
  gemm32(sm + O_B1, 512, 8, xw2, 256, w, l15, lg, x2);
  {
    float beta = beta_p[0];
    #pragma unroll
    for (int mt = 0; mt < 2; mt++)
      #pragma unroll
      for (int nt = 0; nt < 4; nt++){
        int colg = (4*w + nt)*16 + l15;
        float b3v = xcn_b3[colg], xbv = xij_b2[colg];
        #pragma unroll
        for (int r = 0; r < 4; r++){
          int rowg = mt*16 + lg*4 + r;
          float v = (hc[mt][nt][r] + b3v)*beta + (x2[mt][nt][r] + xbv);
          *(u16*)(sm + O_B2 + soff(rowg, colg, 512, 7)) = f2bf(v);
        }
      }
  }
  __syncthreads();
  // Z: relu(z0 @ lin_w1^T + lin_b1) : B2 -> B1
  #pragma unroll
  for (int mt=0;mt<2;mt++) for (int nt=0;nt<4;nt++) acc[mt][nt] = zf;
  gemm32(sm + O_B2, 512, 8, lw1, 256, w, l15, lg, acc);
  store_h(sm + O_B1, acc, lin_b1, true, w, l15, lg);
  __syncthreads();
  // final dot with lin_w2 (8 lanes per edge)
  {
    int e = tid >> 3, li = tid & 7;
    float s = 0.f;
    #pragma unroll
    for (int i = 0; i < 32; i++){
      int c = li*32 + i;
      s += bf2f(*(u16*)(sm + O_B1 + soff(e, c, 512, 7))) * lin_w2[c];
    }
    s += __shfl_xor(s, 1); s += __shfl_xor(s, 2); s += __shfl_xor(s, 4);
    if (li == 0) out[t0 + e] = s + lin_b2[0];
  }
}

// ------------------------------------------------------------------
extern "C" void kernel_launch(void* const* d_in, const int* in_sizes, int n_in,
                              void* d_out, int out_size, void* d_ws, size_t ws_size,
                              hipStream_t stream){
  (void)in_sizes; (void)n_in; (void)out_size; (void)ws_size;
  const float* x        = (const float*)d_in[0];
  const int*   tar_ei   = (const int*)  d_in[1];
  const int*   cn_cols  = (const int*)  d_in[2];
  const int*   cn_cnt   = (const int*)  d_in[3];
  const float* beta     = (const float*)d_in[4];
  const float* tok_w    = (const float*)d_in[5];
  const float* tok_b    = (const float*)d_in[6];
  const float* ln1_g    = (const float*)d_in[7];
  const float* ln1_b    = (const float*)d_in[8];
  const float* qkv_w    = (const float*)d_in[9];
  const float* qkv_b    = (const float*)d_in[10];
  const float* out_w    = (const float*)d_in[11];
  const float* out_b    = (const float*)d_in[12];
  const float* ln2_g    = (const float*)d_in[13];
  const float* ln2_b    = (const float*)d_in[14];
  const float* ff1_w    = (const float*)d_in[15];
  const float* ff1_b    = (const float*)d_in[16];
  const float* ff2_w    = (const float*)d_in[17];
  const float* ff2_b    = (const float*)d_in[18];
  const float* xcn_w1   = (const float*)d_in[19];
  const float* xcn_b1   = (const float*)d_in[20];
  const float* xcn_w2   = (const float*)d_in[21];
  const float* xcn_b2   = (const float*)d_in[22];
  const float* xcn_w3   = (const float*)d_in[23];
  const float* xcn_b3   = (const float*)d_in[24];
  const float* xij_w1   = (const float*)d_in[25];
  const float* xij_b1   = (const float*)d_in[26];
  const float* xij_w2   = (const float*)d_in[27];
  const float* xij_b2   = (const float*)d_in[28];
  const float* lin_w1   = (const float*)d_in[29];
  const float* lin_b1   = (const float*)d_in[30];
  const float* lin_w2   = (const float*)d_in[31];
  const float* lin_b2   = (const float*)d_in[32];

  u16*   wbf = (u16*)d_ws;
  float* xcn = (float*)((char*)d_ws + (size_t)(2u<<20));   // 4 MB
  float* xij = (float*)((char*)d_ws + (size_t)(6u<<20));   // 4 MB

  WP wp;
  wp.p[0]=tok_w; wp.p[1]=qkv_w; wp.p[2]=out_w; wp.p[3]=ff1_w; wp.p[4]=ff2_w;
  wp.p[5]=xcn_w1; wp.p[6]=xcn_w2; wp.p[7]=xcn_w3; wp.p[8]=xij_w1; wp.p[9]=xij_w2;
  wp.p[10]=lin_w1; wp.p[11]=lin_w2;

  k0_convert<<<dim3(2305), dim3(256), 0, stream>>>(wp, wbf);
  k1_fused<<<dim3(TT/2), dim3(256), 0, stream>>>(
      x, tar_ei, cn_cols, cn_cnt, tok_b, ln1_g, ln1_b, qkv_b, out_b,
      ln2_g, ln2_b, ff1_b, ff2_b, wbf, xcn, xij);
  k2_mlp<<<dim3(TT/32), dim3(256), 0, stream>>>(
      xcn, xij, wbf, xcn_b1, xcn_b2, xcn_b3, xij_b1, xij_b2,
      lin_b1, lin_w2, lin_b2, beta, (float*)d_out);
}

// Round 3
// 613.916 us; speedup vs baseline: 1.5317x; 1.3531x over previous
//
#include <hip/hip_runtime.h>
#include <hip/hip_bf16.h>
#include <math.h>

#define DI __device__ __forceinline__

typedef float  f32x4 __attribute__((ext_vector_type(4)));
typedef short  bf8   __attribute__((ext_vector_type(8)));
typedef unsigned short u16;

static constexpr int TT = 8192;   // T edges
static constexpr int KK = 32;     // CN tokens per edge
static constexpr int CC = 128;    // channels

DI u16 f2bf(float x){ union{float f; unsigned u;} v; v.f = x; unsigned r = v.u + 0x7FFFu + ((v.u>>16)&1u); return (u16)(r>>16); }
DI float bf2f(u16 b){ union{unsigned u; float f;} v; v.u = ((unsigned)b)<<16; return v.f; }
DI unsigned pk2(float a, float b){ return (unsigned)f2bf(a) | ((unsigned)f2bf(b)<<16); }
DI f32x4 mfma16(bf8 a, bf8 b, f32x4 c){ return __builtin_amdgcn_mfma_f32_16x16x32_bf16(a, b, c, 0, 0, 0); }
// swizzled LDS byte offset: row-major [*][stride bytes], xor row bits into 16B-slot bits
DI int soff(int r, int c, int stride, int mask){ return r*stride + ((c*2) ^ ((r&mask)<<4)); }

// ------------------------------------------------------------------
// K0: convert weights fp32 -> bf16 blob in MFMA *fragment order*:
// for W[N][K], fragment tile (n16, k32): 64 lanes' 8-elem fragments stored
// contiguously in lane order l = lg*16 + l15:
//   W'[((n16*(K/32) + k32)*64 + l)*8 + e] = W[n16*16 + (l&15)][k32*32 + (l>>4)*8 + e]
// => every wave B-load is 64 consecutive 16B = 1KB coalesced, zero line waste.
// ------------------------------------------------------------------
struct WP { const float* p[12]; };

__global__ void k0_convert(WP wp, u16* __restrict__ dst){
  const int KS[11]  = {512,128,128,128,512,128,256,256,128,256,256};
  const int SH[11]  = {4,2,2,2,4,2,3,3,2,3,3};   // log2(K/32)
  const int OFF[12] = {0,65536,114688,131072,196608,262144,294912,360448,425984,458752,524288,589824};
  int gid = blockIdx.x*256 + threadIdx.x;        // 2305*256 = 590080
  if (gid >= 590080) return;
  if (gid >= 589824){ dst[gid] = f2bf(wp.p[11][gid - 589824]); return; }   // lin_w2 linear
  #pragma unroll
  for (int s = 0; s < 11; s++){
    if (gid < OFF[s+1]){
      int i = gid - OFF[s];
      int e = i & 7, l = (i >> 3) & 63, t = i >> 9;
      int k32 = t & ((1 << SH[s]) - 1), n16 = t >> SH[s];
      int row = n16*16 + (l & 15);
      int col = k32*32 + ((l >> 4) << 3) + e;
      dst[gid] = f2bf(wp.p[s][row*KS[s] + col]);
      return;
    }
  }
}

// ------------------------------------------------------------------
// K1: fused gather + tokenlin + transformer layer + masked mean pool
// 1 block = 2 edges = 64 token rows, 256 threads (4 waves).
// LDS ~52 KB -> 3 blocks/CU.
// ------------------------------------------------------------------
#define O_TOK 0        // [64][128] bf16 sw(256,7)  16K  residual
#define O_H   16384    // [64][128] bf16 sw(256,7)  16K  ln out / xw staging
#define O_RG  32768    // 20K multi-use region:
                       //  phase0: xibuf u32[2][3][64] @+512
                       //  attn:   Q[64][32] sw(64,3) @+0, K @+4096,
                       //          VT[32][64] sw(128,7) @+8192, ATT 4x2K @+12288
                       //  then:   CTX / gelu chunk [64][128] sw(256,7) @+0 (16K)
#define LDS_K1 53248

DI void layernorm64(const char* src, char* dst, const float* __restrict__ g,
                    const float* __restrict__ bta, int tid){
  int r = tid >> 2, q = tid & 3;
  float v[32]; float s = 0.f, sq = 0.f;
  #pragma unroll
  for (int i = 0; i < 4; i++){
    bf8 h8 = *(const bf8*)(src + soff(r, q*32 + i*8, 256, 7));
    #pragma unroll
    for (int j = 0; j < 8; j++){ float f = bf2f((u16)h8[j]); v[i*8+j] = f; s += f; sq += f*f; }
  }
  s  += __shfl_xor(s, 1);  s  += __shfl_xor(s, 2);
  sq += __shfl_xor(sq, 1); sq += __shfl_xor(sq, 2);
  float mu = s * (1.f/128.f);
  float rstd = rsqrtf(sq*(1.f/128.f) - mu*mu + 1e-5f);
  #pragma unroll
  for (int i = 0; i < 4; i++){
    bf8 o;
    #pragma unroll
    for (int j = 0; j < 8; j++){
      int c = q*32 + i*8 + j;
      o[j] = (short)f2bf((v[i*8+j] - mu)*rstd*g[c] + bta[c]);
    }
    *(bf8*)(dst + soff(r, q*32 + i*8, 256, 7)) = o;
  }
}

// n-split GEMM: [64 rows x 128 cols(4 waves x 32)] += LDS_A[64][128] * W'^T
// W' is in fragment order; kt = K/32 of the whole matrix, k0t = k-tile offset.
DI void gemm64(const char* sA, const u16* __restrict__ W, int kt, int k0t,
               int w, int l, int l15, int lg, f32x4 (&acc)[4][2]){
  #pragma unroll
  for (int ks = 0; ks < 4; ks++){
    bf8 b0 = *(const bf8*)(W + (((2*w+0)*kt + k0t + ks)*64 + l)*8);
    bf8 b1 = *(const bf8*)(W + (((2*w+1)*kt + k0t + ks)*64 + l)*8);
    #pragma unroll
    for (int mt = 0; mt < 4; mt++){
      bf8 a = *(const bf8*)(sA + soff(mt*16 + l15, ks*32 + lg*8, 256, 7));
      acc[mt][0] = mfma16(a, b0, acc[mt][0]);
      acc[mt][1] = mfma16(a, b1, acc[mt][1]);
    }
  }
}

__global__ __launch_bounds__(256, 3)
void k1_fused(const float* __restrict__ x, const int* __restrict__ tar_ei,
              const int* __restrict__ cn_cols, const int* __restrict__ cn_counts,
              const float* __restrict__ tok_b,
              const float* __restrict__ ln1_g, const float* __restrict__ ln1_b,
              const float* __restrict__ qkv_b, const float* __restrict__ out_b,
              const float* __restrict__ ln2_g, const float* __restrict__ ln2_b,
              const float* __restrict__ ff1_b, const float* __restrict__ ff2_b,
              const u16* __restrict__ wbf,
              float* __restrict__ xcn_out, float* __restrict__ xij_out)
{
  __shared__ __align__(16) char sm[LDS_K1];
  const int tid = threadIdx.x;
  const int w = tid >> 6, l = tid & 63, l15 = l & 15, lg = l >> 4;
  const int t0 = blockIdx.x * 2;

  const u16* wtok = wbf;            // [128][512] frag-order
  const u16* wqkv = wbf + 65536;    // [384][128]
  const u16* wout = wbf + 114688;   // [128][128]
  const u16* wff1 = wbf + 131072;   // [512][128]
  const u16* wff2 = wbf + 196608;   // [128][512]

  const f32x4 zf = {0.f, 0.f, 0.f, 0.f};
  const int cnt0 = cn_counts[t0], cnt1 = cn_counts[t0 + 1];

  // ---- phase 0a: gather xw -> sH (bf16, swizzled). 4 threads per row.
  {
    int r = tid >> 2, q = tid & 3;
    int col = cn_cols[(t0 + (r >> 5))*KK + (r & 31)];
    const float4* xs = (const float4*)(x + (size_t)col*CC) + q*8;
    #pragma unroll
    for (int i = 0; i < 4; i++){
      float4 a = xs[2*i], b = xs[2*i+1];
      bf8 v;
      v[0]=(short)f2bf(a.x); v[1]=(short)f2bf(a.y); v[2]=(short)f2bf(a.z); v[3]=(short)f2bf(a.w);
      v[4]=(short)f2bf(b.x); v[5]=(short)f2bf(b.y); v[6]=(short)f2bf(b.z); v[7]=(short)f2bf(b.w);
      *(bf8*)(sm + O_H + soff(r, q*32 + i*8, 256, 7)) = v;
    }
  }
  // ---- phase 0b: stage xi/xj/xi*xj broadcast rows + write xij to ws (waves 0-1)
  if (w < 2){
    int e = w, c0 = l*2;
    int ti = tar_ei[t0 + e], tj = tar_ei[TT + t0 + e];
    float vix = x[(size_t)ti*CC + c0], viy = x[(size_t)ti*CC + c0 + 1];
    float vjx = x[(size_t)tj*CC + c0], vjy = x[(size_t)tj*CC + c0 + 1];
    float px = vix*vjx, py = viy*vjy;
    xij_out[(size_t)(t0+e)*CC + c0]     = px;
    xij_out[(size_t)(t0+e)*CC + c0 + 1] = py;
    unsigned* xb = (unsigned*)(sm + O_RG + 512) + e*192;   // [3][64] u32
    xb[l]       = pk2(vix, viy);
    xb[64 + l]  = pk2(vjx, vjy);
    xb[128 + l] = pk2(px, py);
  }
  __syncthreads();

  // ---- tokenlin GEMM, K=512 in 4 chunks.
  // chunk 0 = gathered xw (H); chunks 1-3 = per-edge broadcast rows.
  {
    f32x4 acc[4][2];
    #pragma unroll
    for (int mt = 0; mt < 4; mt++){ acc[mt][0] = zf; acc[mt][1] = zf; }
    gemm64(sm + O_H, wtok, 16, 0, w, l, l15, lg, acc);
    #pragma unroll
    for (int c = 1; c < 4; c++){
      #pragma unroll
      for (int ks = 0; ks < 4; ks++){
        bf8 b0 = *(const bf8*)(wtok + (((2*w+0)*16 + c*4 + ks)*64 + l)*8);
        bf8 b1 = *(const bf8*)(wtok + (((2*w+1)*16 + c*4 + ks)*64 + l)*8);
        #pragma unroll
        for (int mt = 0; mt < 4; mt++){
          int e = mt >> 1;
          bf8 a = *(const bf8*)(sm + O_RG + 512 + (e*192 + (c-1)*64)*4 + (ks*32 + lg*8)*2);
          acc[mt][0] = mfma16(a, b0, acc[mt][0]);
          acc[mt][1] = mfma16(a, b1, acc[mt][1]);
        }
      }
    }
    #pragma unroll
    for (int mt = 0; mt < 4; mt++){
      #pragma unroll
      for (int nt = 0; nt < 2; nt++){
        int colg = (2*w + nt)*16 + l15;
        float tb = tok_b[colg];
        #pragma unroll
        for (int r = 0; r < 4; r++){
          int rowg = mt*16 + lg*4 + r;
          float v = fmaxf(acc[mt][nt][r] + tb, 0.f);
          *(u16*)(sm + O_TOK + soff(rowg, colg, 256, 7)) = f2bf(v);
        }
      }
    }
  }
  __syncthreads();

  // ---- LN1: sTok -> sH
  layernorm64(sm + O_TOK, sm + O_H, ln1_g, ln1_b, tid);
  __syncthreads();

  // ---- attention: 4 chunks of 2 heads; ctx accumulated in packed regs
  unsigned pk[4][4];
  const int e_w = w >> 1, hh_w = w & 1;
  const int cnt_e = (e_w == 0) ? cnt0 : cnt1;
  char* const sQ  = sm + O_RG;
  char* const sK  = sm + O_RG + 4096;
  char* const sVT = sm + O_RG + 8192;
  char* const sAT = sm + O_RG + 12288 + w*2048;
  #pragma unroll
  for (int hc2 = 0; hc2 < 4; hc2++){
    // qkv: 6 tiles (q/k/v x 2 heads), round-robin over 4 waves
    for (int tt = w; tt < 6; tt += 4){
      int kind = tt >> 1, sub = tt & 1;
      int n16 = kind*8 + hc2*2 + sub;
      f32x4 acc[4];
      #pragma unroll
      for (int mt = 0; mt < 4; mt++) acc[mt] = zf;
      #pragma unroll
      for (int ks = 0; ks < 4; ks++){
        bf8 b = *(const bf8*)(wqkv + ((n16*4 + ks)*64 + l)*8);
        #pragma unroll
        for (int mt = 0; mt < 4; mt++){
          bf8 a = *(const bf8*)(sm + O_H + soff(mt*16 + l15, ks*32 + lg*8, 256, 7));
          acc[mt] = mfma16(a, b, acc[mt]);
        }
      }
      float bias = qkv_b[n16*16 + l15];
      #pragma unroll
      for (int mt = 0; mt < 4; mt++){
        #pragma unroll
        for (int r = 0; r < 4; r++){
          int rowg = mt*16 + lg*4 + r;
          u16 hv = f2bf(acc[mt][r] + bias);
          if (kind == 0)      *(u16*)(sQ  + soff(rowg, sub*16 + l15, 64, 3)) = hv;
          else if (kind == 1) *(u16*)(sK  + soff(rowg, sub*16 + l15, 64, 3)) = hv;
          else                *(u16*)(sVT + soff(sub*16 + l15, rowg, 128, 7)) = hv;
        }
      }
    }
    __syncthreads();

    // per-wave attention: edge e_w, head hh_w of this chunk
    {
      bf8 z8 = {0,0,0,0,0,0,0,0};
      bf8 qa[2], kb[2];
      #pragma unroll
      for (int mt = 0; mt < 2; mt++)
        qa[mt] = (lg < 2) ? *(const bf8*)(sQ + soff(e_w*32 + mt*16 + l15, hh_w*16 + lg*8, 64, 3)) : z8;
      #pragma unroll
      for (int nt = 0; nt < 2; nt++)
        kb[nt] = (lg < 2) ? *(const bf8*)(sK + soff(e_w*32 + nt*16 + l15, hh_w*16 + lg*8, 64, 3)) : z8;
      f32x4 sc[2][2];
      #pragma unroll
      for (int mt = 0; mt < 2; mt++)
        #pragma unroll
        for (int nt = 0; nt < 2; nt++)
          sc[mt][nt] = mfma16(qa[mt], kb[nt], zf);
      float pr[2][2][4];
      #pragma unroll
      for (int mt = 0; mt < 2; mt++)
        #pragma unroll
        for (int nt = 0; nt < 2; nt++)
          #pragma unroll
          for (int r = 0; r < 4; r++)
            pr[mt][nt][r] = (nt*16 + l15 < cnt_e) ? sc[mt][nt][r]*0.25f : -1e9f;
      #pragma unroll
      for (int mt = 0; mt < 2; mt++)
        #pragma unroll
        for (int r = 0; r < 4; r++){
          float m = fmaxf(pr[mt][0][r], pr[mt][1][r]);
          m = fmaxf(m, __shfl_xor(m, 1)); m = fmaxf(m, __shfl_xor(m, 2));
          m = fmaxf(m, __shfl_xor(m, 4)); m = fmaxf(m, __shfl_xor(m, 8));
          float e0 = __expf(pr[mt][0][r] - m), e1 = __expf(pr[mt][1][r] - m);
          float ss = e0 + e1;
          ss += __shfl_xor(ss, 1); ss += __shfl_xor(ss, 2);
          ss += __shfl_xor(ss, 4); ss += __shfl_xor(ss, 8);
          float inv = 1.f / ss;
          int rowl = mt*16 + lg*4 + r;
          *(u16*)(sAT + soff(rowl, l15,      64, 3)) = f2bf(e0*inv);
          *(u16*)(sAT + soff(rowl, 16 + l15, 64, 3)) = f2bf(e1*inv);
        }
      // PV: ctx[32 rows][16 dh] for this head
      bf8 vb = *(const bf8*)(sVT + soff(hh_w*16 + l15, e_w*32 + lg*8, 128, 7));
      #pragma unroll
      for (int mtp = 0; mtp < 2; mtp++){
        bf8 pa = *(const bf8*)(sAT + soff(mtp*16 + l15, lg*8, 64, 3));
        f32x4 cx = mfma16(pa, vb, zf);
        pk[hc2][mtp*2+0] = pk2(cx[0], cx[1]);
        pk[hc2][mtp*2+1] = pk2(cx[2], cx[3]);
      }
    }
    __syncthreads();
  }

  // ---- write ctx fragments to CTX region (overlays Q/K/VT/ATT)
  #pragma unroll
  for (int hc = 0; hc < 4; hc++){
    int head = hc*2 + hh_w;
    #pragma unroll
    for (int mtp = 0; mtp < 2; mtp++)
      #pragma unroll
      for (int i = 0; i < 2; i++){
        unsigned pv = pk[hc][mtp*2+i];
        int rowg = e_w*32 + mtp*16 + lg*4 + i*2;
        *(u16*)(sm + O_RG + soff(rowg,     head*16 + l15, 256, 7)) = (u16)(pv & 0xffffu);
        *(u16*)(sm + O_RG + soff(rowg + 1, head*16 + l15, 256, 7)) = (u16)(pv >> 16);
      }
  }
  __syncthreads();

  // ---- out projection + residual (RMW sTok)
  {
    f32x4 acc[4][2];
    #pragma unroll
    for (int mt = 0; mt < 4; mt++){ acc[mt][0] = zf; acc[mt][1] = zf; }
    gemm64(sm + O_RG, wout, 4, 0, w, l, l15, lg, acc);
    #pragma unroll
    for (int mt = 0; mt < 4; mt++){
      #pragma unroll
      for (int nt = 0; nt < 2; nt++){
        int colg = (2*w + nt)*16 + l15;
        float ob = out_b[colg];
        #pragma unroll
        for (int r = 0; r < 4; r++){
          int rowg = mt*16 + lg*4 + r;
          u16* tp = (u16*)(sm + O_TOK + soff(rowg, colg, 256, 7));
          float v = acc[mt][nt][r] + ob + bf2f(*tp);
          *tp = f2bf(v);
        }
      }
    }
  }
  __syncthreads();

  // ---- LN2: sTok -> sH
  layernorm64(sm + O_TOK, sm + O_H, ln2_g, ln2_b, tid);
  __syncthreads();

  // ---- FF: 4 column chunks of 128; fp32 accumulator carried across chunks
  f32x4 acc2[4][2];
  #pragma unroll
  for (int mt = 0; mt < 4; mt++){ acc2[mt][0] = zf; acc2[mt][1] = zf; }
  for (int c = 0; c < 4; c++){
    f32x4 acc1[4][2];
    #pragma unroll
    for (int mt = 0; mt < 4; mt++){ acc1[mt][0] = zf; acc1[mt][1] = zf; }
    gemm64(sm + O_H, wff1 + (size_t)(c*128)*128, 4, 0, w, l, l15, lg, acc1);
    #pragma unroll
    for (int mt = 0; mt < 4; mt++){
      #pragma unroll
      for (int nt = 0; nt < 2; nt++){
        int colg = (2*w + nt)*16 + l15;
        float fb = ff1_b[c*128 + colg];
        #pragma unroll
        for (int r = 0; r < 4; r++){
          int rowg = mt*16 + lg*4 + r;
          float vv = acc1[mt][nt][r] + fb;
          vv = 0.5f*vv*(1.f + erff(vv*0.70710678118654752f));   // exact gelu
          *(u16*)(sm + O_RG + soff(rowg, colg, 256, 7)) = f2bf(vv);
        }
      }
    }
    __syncthreads();
    gemm64(sm + O_RG, wff2, 16, c*4, w, l, l15, lg, acc2);
    __syncthreads();
  }

  // ---- final residual + masked mean pool straight from fp32 fragments
  {
    float pool[2][2] = {};
    #pragma unroll
    for (int mt = 0; mt < 4; mt++){
      int e = mt >> 1;
      int cnt_m = (e == 0) ? cnt0 : cnt1;
      #pragma unroll
      for (int nt = 0; nt < 2; nt++){
        int colg = (2*w + nt)*16 + l15;
        float fb = ff2_b[colg];
        #pragma unroll
        for (int r = 0; r < 4; r++){
          int rowg = mt*16 + lg*4 + r;
          float tp = bf2f(*(u16*)(sm + O_TOK + soff(rowg, colg, 256, 7)));
          float v = acc2[mt][nt][r] + fb + tp;
          if ((rowg & 31) < cnt_m) pool[e][nt] += v;
        }
      }
    }
    #pragma unroll
    for (int e = 0; e < 2; e++){
      #pragma unroll
      for (int nt = 0; nt < 2; nt++){
        float v = pool[e][nt];
        v += __shfl_xor(v, 16);
        v += __shfl_xor(v, 32);
        if (lg == 0){
          int cn = (e == 0) ? cnt0 : cnt1;
          float denom = (float)(cn > 0 ? cn : 1);
          xcn_out[(size_t)(t0 + e)*CC + 32*w + nt*16 + l15] = v / denom;
        }
      }
    }
  }
}

// ------------------------------------------------------------------
// K2: edge MLPs, 32 edges per block, 256 blocks. 4 aliased buffers, 48 KB.
// ------------------------------------------------------------------
DI void gemm32(const char* sA, int astride, int ktiles, const u16* __restrict__ W,
               int w, int l, int l15, int lg, f32x4 (&acc)[2][4]){
  for (int ks = 0; ks < ktiles; ks++){
    bf8 a0 = *(const bf8*)(sA + soff(0*16 + l15, ks*32 + lg*8, astride, 7));
    bf8 a1 = *(const bf8*)(sA + soff(1*16 + l15, ks*32 + lg*8, astride, 7));
    #pragma unroll
    for (int nt = 0; nt < 4; nt++){
      bf8 b = *(const bf8*)(W + ((((4*w+nt)*ktiles + ks))*64 + l)*8);
      acc[0][nt] = mfma16(a0, b, acc[0][nt]);
      acc[1][nt] = mfma16(a1, b, acc[1][nt]);
    }
  }
}

DI void store_h(char* dst, f32x4 (&acc)[2][4], const float* __restrict__ bias, bool relu,
                int w, int l15, int lg){
  #pragma unroll
  for (int mt = 0; mt < 2; mt++)
    #pragma unroll
    for (int nt = 0; nt < 4; nt++){
      int colg = (4*w + nt)*16 + l15;
      float bb = bias[colg];
      #pragma unroll
      for (int r = 0; r < 4; r++){
        int rowg = mt*16 + lg*4 + r;
        float v = acc[mt][nt][r] + bb;
        if (relu) v = fmaxf(v, 0.f);
        *(u16*)(dst + soff(rowg, colg, 512, 7)) = f2bf(v);
      }
    }
}

__global__ __launch_bounds__(256, 3)
void k2_mlp(const float* __restrict__ xcn, const float* __restrict__ xij,
            const u16* __restrict__ wbf,
            const float* __restrict__ xcn_b1, const float* __restrict__ xcn_b2,
            const float* __restrict__ xcn_b3, const float* __restrict__ xij_b1,
            const float* __restrict__ xij_b2, const float* __restrict__ lin_b1,
            const float* __restrict__ lin_w2, const float* __restrict__ lin_b2,
            const float* __restrict__ beta_p, float* __restrict__ out)
{
  __shared__ __align__(16) char sm[49152];
  const int O_A = 0, O_X = 8192, O_B1 = 16384, O_B2 = 32768;
  const u16* w1  = wbf + 262144;   // [256][128] frag-order
  const u16* w2  = wbf + 294912;   // [256][256]
  const u16* w3  = wbf + 360448;   // [256][256]
  const u16* xw1 = wbf + 425984;   // [256][128]
  const u16* xw2 = wbf + 458752;   // [256][256]
  const u16* lw1 = wbf + 524288;   // [256][256]
  const int tid = threadIdx.x;
  const int w = tid >> 6, l = tid & 63, l15 = l & 15, lg = (tid & 63) >> 4;
  const int t0 = blockIdx.x * 32;
  const f32x4 zf = {0.f,0.f,0.f,0.f};

  // stage xcn, xij as bf16 (swizzled, stride 256)
  {
    int r = tid >> 3, ci0 = (tid & 7) * 16;
    const float4* ps = (const float4*)(xcn + (size_t)(t0 + r)*CC + ci0);
    const float4* qs = (const float4*)(xij + (size_t)(t0 + r)*CC + ci0);
    #pragma unroll
    for (int h = 0; h < 2; h++){
      float4 a = ps[2*h], b = ps[2*h+1];
      bf8 v;
      v[0]=(short)f2bf(a.x); v[1]=(short)f2bf(a.y); v[2]=(short)f2bf(a.z); v[3]=(short)f2bf(a.w);
      v[4]=(short)f2bf(b.x); v[5]=(short)f2bf(b.y); v[6]=(short)f2bf(b.z); v[7]=(short)f2bf(b.w);
      *(bf8*)(sm + O_A + soff(r, ci0 + h*8, 256, 7)) = v;
      float4 cq = qs[2*h], dq = qs[2*h+1];
      bf8 u;
      u[0]=(short)f2bf(cq.x); u[1]=(short)f2bf(cq.y); u[2]=(short)f2bf(cq.z); u[3]=(short)f2bf(cq.w);
      u[4]=(short)f2bf(dq.x); u[5]=(short)f2bf(dq.y); u[6]=(short)f2bf(dq.z); u[7]=(short)f2bf(dq.w);
      *(bf8*)(sm + O_X + soff(r, ci0 + h*8, 256, 7)) = u;
    }
  }
  __syncthreads();

  f32x4 acc[2][4];
  // L1: relu(xcn @ w1^T + b1) : A -> B1
  #pragma unroll
  for (int mt=0;mt<2;mt++) for (int nt=0;nt<4;nt++) acc[mt][nt] = zf;
  gemm32(sm + O_A, 256, 4, w1, w, l, l15, lg, acc);
  store_h(sm + O_B1, acc, xcn_b1, true, w, l15, lg);
  __syncthreads();
  // L2: relu(h1 @ w2^T + b2) : B1 -> B2
  #pragma unroll
  for (int mt=0;mt<2;mt++) for (int nt=0;nt<4;nt++) acc[mt][nt] = zf;
  gemm32(sm + O_B1, 512, 8, w2, w, l, l15, lg, acc);
  store_h(sm + O_B2, acc, xcn_b2, true, w, l15, lg);
  __syncthreads();
  // L3 (no act) B2 -> regs; X1: X -> B1 (B1 free after L2 barrier)
  f32x4 hc[2][4];
  #pragma unroll
  for (int mt=0;mt<2;mt++) for (int nt=0;nt<4;nt++) hc[mt][nt] = zf;
  gemm32(sm + O_B2, 512, 8, w3, w, l, l15, lg, hc);
  #pragma unroll
  for (int mt=0;mt<2;mt++) for (int nt=0;nt<4;nt++) acc[mt][nt] = zf;
  gemm32(sm + O_X, 256, 4, xw1, w, l, l15, lg, acc);
  store_h(sm + O_B1, acc, xij_b1, true, w, l15, lg);
  __syncthreads();
  // X2 (no act): B1 -> regs; combine -> B2 (all waves past L3 reads)
  f32x4 x2[2][4];
  #pragma unroll
  for (int mt=0;mt<2;mt++) for (int nt=0;nt<4;nt++) x2[mt][nt] = zf;
  gemm32(sm + O_B1, 512, 8, xw2, w, l, l15, lg, x2);
  {
    float beta = beta_p[0];
    #pragma unroll
    for (int mt = 0; mt < 2; mt++)
      #pragma unroll
      for (int nt = 0; nt < 4; nt++){
        int colg = (4*w + nt)*16 + l15;
        float b3v = xcn_b3[colg], xbv = xij_b2[colg];
        #pragma unroll
        for (int r = 0; r < 4; r++){
          int rowg = mt*16 + lg*4 + r;
          float v = (hc[mt][nt][r] + b3v)*beta + (x2[mt][nt][r] + xbv);
          *(u16*)(sm + O_B2 + soff(rowg, colg, 512, 7)) = f2bf(v);
        }
      }
  }
  __syncthreads();
  // Z: relu(z0 @ lin_w1^T + lin_b1) : B2 -> B1
  #pragma unroll
  for (int mt=0;mt<2;mt++) for (int nt=0;nt<4;nt++) acc[mt][nt] = zf;
  gemm32(sm + O_B2, 512, 8, lw1, w, l, l15, lg, acc);
  store_h(sm + O_B1, acc, lin_b1, true, w, l15, lg);
  __syncthreads();
  // final dot with lin_w2 (8 lanes per edge)
  {
    int e = tid >> 3, li = tid & 7;
    float s = 0.f;
    #pragma unroll
    for (int i = 0; i < 32; i++){
      int c = li*32 + i;
      s += bf2f(*(u16*)(sm + O_B1 + soff(e, c, 512, 7))) * lin_w2[c];
    }
    s += __shfl_xor(s, 1); s += __shfl_xor(s, 2); s += __shfl_xor(s, 4);
    if (li == 0) out[t0 + e] = s + lin_b2[0];
  }
}

// ------------------------------------------------------------------
extern "C" void kernel_launch(void* const* d_in, const int* in_sizes, int n_in,
                              void* d_out, int out_size, void* d_ws, size_t ws_size,
                              hipStream_t stream){
  (void)in_sizes; (void)n_in; (void)out_size; (void)ws_size;
  const float* x        = (const float*)d_in[0];
  const int*   tar_ei   = (const int*)  d_in[1];
  const int*   cn_cols  = (const int*)  d_in[2];
  const int*   cn_cnt   = (const int*)  d_in[3];
  const float* beta     = (const float*)d_in[4];
  const float* tok_w    = (const float*)d_in[5];
  const float* tok_b    = (const float*)d_in[6];
  const float* ln1_g    = (const float*)d_in[7];
  const float* ln1_b    = (const float*)d_in[8];
  const float* qkv_w    = (const float*)d_in[9];
  const float* qkv_b    = (const float*)d_in[10];
  const float* out_w    = (const float*)d_in[11];
  const float* out_b    = (const float*)d_in[12];
  const float* ln2_g    = (const float*)d_in[13];
  const float* ln2_b    = (const float*)d_in[14];
  const float* ff1_w    = (const float*)d_in[15];
  const float* ff1_b    = (const float*)d_in[16];
  const float* ff2_w    = (const float*)d_in[17];
  const float* ff2_b    = (const float*)d_in[18];
  const float* xcn_w1   = (const float*)d_in[19];
  const float* xcn_b1   = (const float*)d_in[20];
  const float* xcn_w2   = (const float*)d_in[21];
  const float* xcn_b2   = (const float*)d_in[22];
  const float* xcn_w3   = (const float*)d_in[23];
  const float* xcn_b3   = (const float*)d_in[24];
  const float* xij_w1   = (const float*)d_in[25];
  const float* xij_b1   = (const float*)d_in[26];
  const float* xij_w2   = (const float*)d_in[27];
  const float* xij_b2   = (const float*)d_in[28];
  const float* lin_w1   = (const float*)d_in[29];
  const float* lin_b1   = (const float*)d_in[30];
  const float* lin_w2   = (const float*)d_in[31];
  const float* lin_b2   = (const float*)d_in[32];

  u16*   wbf = (u16*)d_ws;
  float* xcn = (float*)((char*)d_ws + (size_t)(2u<<20));   // 4 MB
  float* xij = (float*)((char*)d_ws + (size_t)(6u<<20));   // 4 MB

  WP wp;
  wp.p[0]=tok_w; wp.p[1]=qkv_w; wp.p[2]=out_w; wp.p[3]=ff1_w; wp.p[4]=ff2_w;
  wp.p[5]=xcn_w1; wp.p[6]=xcn_w2; wp.p[7]=xcn_w3; wp.p[8]=xij_w1; wp.p[9]=xij_w2;
  wp.p[10]=lin_w1; wp.p[11]=lin_w2;

  k0_convert<<<dim3(2305), dim3(256), 0, stream>>>(wp, wbf);
  k1_fused<<<dim3(TT/2), dim3(256), 0, stream>>>(
      x, tar_ei, cn_cols, cn_cnt, tok_b, ln1_g, ln1_b, qkv_b, out_b,
      ln2_g, ln2_b, ff1_b, ff2_b, wbf, xcn, xij);
  k2_mlp<<<dim3(TT/32), dim3(256), 0, stream>>>(
      xcn, xij, wbf, xcn_b1, xcn_b2, xcn_b3, xij_b1, xij_b2,
      lin_b1, lin_w2, lin_b2, beta, (float*)d_out);
}